// Round 12
// baseline (163.450 us; speedup 1.0000x reference)
//
#include <hip/hip_runtime.h>
#include <hip/hip_fp16.h>

#define N 1024
#define D 128

// ---------------- proj: Q,K (f32) + Ah,Bh (f16) = z@{Wq,Wk,W1a,W1b} ----------------
__global__ __launch_bounds__(256) void proj_kernel(
    const float* __restrict__ z,
    const float* __restrict__ Wq, const float* __restrict__ bq,
    const float* __restrict__ Wk, const float* __restrict__ bk,
    const float* __restrict__ W1, const float* __restrict__ b1,
    float* __restrict__ Q, float* __restrict__ Kx,
    __half* __restrict__ Ah, __half* __restrict__ Bh)
{
    const int d  = threadIdx.x & (D - 1);
    const int h  = threadIdx.x >> 7;              // wave-uniform: 0 -> Q/K, 1 -> A/B
    const int r0 = blockIdx.x * 8;
    const float* __restrict__ Wa = h ? W1           : Wq;
    const float* __restrict__ Wb = h ? (W1 + D * D) : Wk;

    float acc0[8] = {0,0,0,0,0,0,0,0};
    float acc1[8] = {0,0,0,0,0,0,0,0};

    for (int c = 0; c < D / 4; ++c) {
        float4 zr[8];
#pragma unroll
        for (int r = 0; r < 8; ++r)
            zr[r] = *(const float4*)&z[(r0 + r) * D + c * 4];
#pragma unroll
        for (int q = 0; q < 4; ++q) {
            const int k = c * 4 + q;
            const float wa = Wa[k * D + d];
            const float wb = Wb[k * D + d];
#pragma unroll
            for (int r = 0; r < 8; ++r) {
                const float zv = (q == 0) ? zr[r].x : (q == 1) ? zr[r].y : (q == 2) ? zr[r].z : zr[r].w;
                acc0[r] = fmaf(zv, wa, acc0[r]);
                acc1[r] = fmaf(zv, wb, acc1[r]);
            }
        }
    }
    if (h == 0) {
        const float c0 = bq[d], c1 = bk[d];
        const float scale = 0.08838834764831845f;   // 1/sqrt(128), folded into Q
#pragma unroll
        for (int r = 0; r < 8; ++r) {
            Q [(r0 + r) * D + d] = (acc0[r] + c0) * scale;
            Kx[(r0 + r) * D + d] = acc1[r] + c1;
        }
    } else {
        const float c0 = b1[d];
#pragma unroll
        for (int r = 0; r < 8; ++r) {
            Ah[(r0 + r) * D + d] = __float2half(acc0[r] + c0);   // b1 folded
            Bh[(r0 + r) * D + d] = __float2half(acc1[r]);
        }
    }
}

// ---------------- scores: S = (Q K^T) * exp(-dist), 32x32 tile (known-good) ----------------
__global__ __launch_bounds__(256) void score_kernel(
    const float* __restrict__ Q, const float* __restrict__ Kx,
    const float* __restrict__ dist, float* __restrict__ S)
{
    __shared__ float Qs[32 * 33 * 4];
    __shared__ float Ks[32 * 33 * 4];
    const int tid = threadIdx.x;
    const int bi = blockIdx.y * 32, bj = blockIdx.x * 32;
    const int tx = tid & 15, ty = tid >> 4;

#pragma unroll
    for (int t = 0; t < 4; ++t) {
        const int e = t * 256 + tid;
        const int row = e >> 5, c = e & 31;
        *(float4*)&Qs[(row * 33 + c) * 4] = *(const float4*)&Q [(size_t)(bi + row) * D + c * 4];
        *(float4*)&Ks[(row * 33 + c) * 4] = *(const float4*)&Kx[(size_t)(bj + row) * D + c * 4];
    }
    __syncthreads();

    const float4* Qs4 = (const float4*)Qs;
    const float4* Ks4 = (const float4*)Ks;
    float a00 = 0.f, a01 = 0.f, a10 = 0.f, a11 = 0.f;

#pragma unroll 4
    for (int c = 0; c < 32; ++c) {
        const float4 q0 = Qs4[ty * 33 + c];
        const float4 q1 = Qs4[(ty + 16) * 33 + c];
        const float4 k0 = Ks4[tx * 33 + c];
        const float4 k1 = Ks4[(tx + 16) * 33 + c];
        a00 = fmaf(q0.x, k0.x, a00); a00 = fmaf(q0.y, k0.y, a00); a00 = fmaf(q0.z, k0.z, a00); a00 = fmaf(q0.w, k0.w, a00);
        a01 = fmaf(q0.x, k1.x, a01); a01 = fmaf(q0.y, k1.y, a01); a01 = fmaf(q0.z, k1.z, a01); a01 = fmaf(q0.w, k1.w, a01);
        a10 = fmaf(q1.x, k0.x, a10); a10 = fmaf(q1.y, k0.y, a10); a10 = fmaf(q1.z, k0.z, a10); a10 = fmaf(q1.w, k0.w, a10);
        a11 = fmaf(q1.x, k1.x, a11); a11 = fmaf(q1.y, k1.y, a11); a11 = fmaf(q1.z, k1.z, a11); a11 = fmaf(q1.w, k1.w, a11);
    }

    const int i0 = bi + ty, i1 = bi + ty + 16;
    const int j0 = bj + tx, j1 = bj + tx + 16;
    S[(size_t)i0 * N + j0] = a00 * __expf(-dist[(size_t)i0 * N + j0]);
    S[(size_t)i0 * N + j1] = a01 * __expf(-dist[(size_t)i0 * N + j1]);
    S[(size_t)i1 * N + j0] = a10 * __expf(-dist[(size_t)i1 * N + j0]);
    S[(size_t)i1 * N + j1] = a11 * __expf(-dist[(size_t)i1 * N + j1]);
}

// ---------------- softmax + top-32 per row; one wave per row (known-good) ----------------
__global__ __launch_bounds__(256) void topk_kernel(float* buf)
{
    const int lane = threadIdx.x & 63;
    const int row  = blockIdx.x * 4 + (threadIdx.x >> 6);
    float* sr = buf + (size_t)row * N;

    float v[16];
#pragma unroll
    for (int c = 0; c < 4; ++c) {
        const float4 f = *(const float4*)&sr[(c * 64 + lane) * 4];
        v[c * 4 + 0] = f.x; v[c * 4 + 1] = f.y; v[c * 4 + 2] = f.z; v[c * 4 + 3] = f.w;
    }
    float m = v[0];
#pragma unroll
    for (int e = 1; e < 16; ++e) m = fmaxf(m, v[e]);
#pragma unroll
    for (int off = 1; off < 64; off <<= 1) m = fmaxf(m, __shfl_xor(m, off));
    float sum = 0.f;
#pragma unroll
    for (int e = 0; e < 16; ++e) sum += __expf(v[e] - m);
#pragma unroll
    for (int off = 1; off < 64; off <<= 1) sum += __shfl_xor(sum, off);
    const float inv = 1.0f / sum;

    unsigned long long key[16];
#pragma unroll
    for (int e = 0; e < 16; ++e) {
        const int j = (((e >> 2) * 64 + lane) * 4) + (e & 3);
        unsigned u = __float_as_uint(v[e]);
        u = (u & 0x80000000u) ? ~u : (u | 0x80000000u);
        key[e] = ((unsigned long long)u << 32) | (unsigned)(N - 1 - j);
    }
    unsigned flags = 0;
    for (int it = 0; it < 32; ++it) {
        unsigned long long best = key[0];
#pragma unroll
        for (int e = 1; e < 16; ++e) best = (key[e] > best) ? key[e] : best;
#pragma unroll
        for (int off = 1; off < 64; off <<= 1) {
            const unsigned long long o = __shfl_xor(best, off);
            if (o > best) best = o;
        }
#pragma unroll
        for (int e = 0; e < 16; ++e)
            if (key[e] == best) { flags |= 1u << e; key[e] = 0ull; }
    }
#pragma unroll
    for (int c = 0; c < 4; ++c) {
        float4 o;
        o.x = (flags & (1u << (c * 4 + 0))) ? __expf(v[c * 4 + 0] - m) * inv : 0.f;
        o.y = (flags & (1u << (c * 4 + 1))) ? __expf(v[c * 4 + 1] - m) * inv : 0.f;
        o.z = (flags & (1u << (c * 4 + 2))) ? __expf(v[c * 4 + 2] - m) * inv : 0.f;
        o.w = (flags & (1u << (c * 4 + 3))) ? __expf(v[c * 4 + 3] - m) * inv : 0.f;
        *(float4*)&sr[(c * 64 + lane) * 4] = o;
    }
}

// ---------------- pairwise gelu classifier + 3-way softmax, f16x2, rsqrt-sigmoid ----------------
// gelu(x) = x * (0.5 + 0.5*u*rsqrt(1+u^2)),  u = x*(u1 + u3 x^2 + u5 x^4)
//   -> ONE trans (rsqrt) per half instead of two (exp+rcp). Exact saturation at +-inf.
//   Coeffs: Taylor match at 0 + midrange balance; max |gelu err| ~ 2.6e-3 on |x|<=6.
//   x clamped to [-6,6]: u(6)=191 -> u^2=36.5k fits f16; |a+b| <= ~6.2 worst case.
union H2x4 { uint4 u; __half2 h[4]; };

typedef _Float16 v2h __attribute__((ext_vector_type(2)));
union H2V { __half2 h; v2h v; };

__device__ __forceinline__ __half2 clamp2(__half2 x, v2h lo, v2h hi) {
    H2V t; t.h = x;
    t.v = __builtin_elementwise_min(__builtin_elementwise_max(t.v, lo), hi);
    return t.h;
}

__device__ __forceinline__ float fdot2_acc(__half2 a, __half2 b, float c) {
#if __has_builtin(__builtin_amdgcn_fdot2)
    H2V ua, ub;
    ua.h = a; ub.h = b;
    return __builtin_amdgcn_fdot2(ua.v, ub.v, c, false);
#else
    return fmaf(__low2float(a), __low2float(b),
           fmaf(__high2float(a), __high2float(b), c));
#endif
}

#define HP 136   // halves pitch: 272 B rows (16B-aligned)

__global__ __launch_bounds__(256) void pair_kernel(
    const __half* __restrict__ Ah, const __half* __restrict__ Bh,
    const float* __restrict__ W2, const float* __restrict__ b2,
    float* __restrict__ out)
{
    __shared__ __align__(16) __half AsH[32 * HP];
    __shared__ __align__(16) __half BsH[32 * HP];
    __shared__ __align__(16) __half2 Wh[3][68];
    const int tid = threadIdx.x;
    const int bi = blockIdx.y * 32, bj = blockIdx.x * 32;
    const int tx = tid & 15, ty = tid >> 4;

#pragma unroll
    for (int t = 0; t < 2; ++t) {
        const int e = t * 256 + tid;
        const int row = e >> 4, c = e & 15;
        *(uint4*)&AsH[row * HP + c * 8] = *(const uint4*)&Ah[(size_t)(bi + row) * D + c * 8];
        *(uint4*)&BsH[row * HP + c * 8] = *(const uint4*)&Bh[(size_t)(bj + row) * D + c * 8];
    }
    if (tid < 192) {
        const int cls = tid >> 6, dp = tid & 63;
        Wh[cls][dp] = __floats2half2_rn(W2[6 * dp + cls], W2[6 * dp + 3 + cls]);
    }
    const float bb0 = b2[0], bb1 = b2[1], bb2 = b2[2];
    __syncthreads();

    float acc[4][3];
#pragma unroll
    for (int p = 0; p < 4; ++p) { acc[p][0] = bb0; acc[p][1] = bb1; acc[p][2] = bb2; }

    const __half2 U1   = __float2half2_rn(0.7978846f);
    const __half2 U3   = __float2half2_rn(0.120986f);
    const __half2 U5   = __float2half2_rn(0.0206f);
    const __half2 HLF  = __float2half2_rn(0.5f);
    const __half2 ONE  = __float2half2_rn(1.0f);
    const v2h XHI = { (_Float16)6.0f,  (_Float16)6.0f  };
    const v2h XLO = { (_Float16)-6.0f, (_Float16)-6.0f };

#pragma unroll 4
    for (int c = 0; c < 16; ++c) {      // 16 chunks x 8 d
        H2x4 a0, a1, b0, b1, w0, w1, w2;
        a0.u = *(const uint4*)&AsH[ty * HP + c * 8];
        a1.u = *(const uint4*)&AsH[(ty + 16) * HP + c * 8];
        b0.u = *(const uint4*)&BsH[tx * HP + c * 8];
        b1.u = *(const uint4*)&BsH[(tx + 16) * HP + c * 8];
        w0.u = *(const uint4*)&Wh[0][c * 4];
        w1.u = *(const uint4*)&Wh[1][c * 4];
        w2.u = *(const uint4*)&Wh[2][c * 4];
#pragma unroll
        for (int dp = 0; dp < 4; ++dp) {
            const __half2 aa[2] = { a0.h[dp], a1.h[dp] };
            const __half2 bb[2] = { b0.h[dp], b1.h[dp] };
            const __half2 wc0 = w0.h[dp], wc1 = w1.h[dp], wc2 = w2.h[dp];
#pragma unroll
            for (int ii = 0; ii < 2; ++ii)
#pragma unroll
                for (int jj = 0; jj < 2; ++jj) {
                    __half2 x = __hadd2(aa[ii], bb[jj]);
                    x = clamp2(x, XLO, XHI);                  // |x|<=6: no f16 overflow in u^2
                    const __half2 s = __hmul2(x, x);
                    const __half2 e = __hmul2(s, s);
                    __half2 q = __hfma2(U3, s, U1);
                    q = __hfma2(U5, e, q);
                    const __half2 u = __hmul2(x, q);
                    const __half2 dnm = __hfma2(u, u, ONE);
                    const __half2 r = h2rsqrt(dnm);           // the single trans op
                    const __half2 w = __hmul2(u, r);
                    const __half2 v = __hfma2(HLF, w, HLF);   // Phi(x)
                    const __half2 g = __hmul2(x, v);          // gelu
                    float* l = acc[ii * 2 + jj];
                    l[0] = fdot2_acc(g, wc0, l[0]);
                    l[1] = fdot2_acc(g, wc1, l[1]);
                    l[2] = fdot2_acc(g, wc2, l[2]);
                }
        }
    }

#pragma unroll
    for (int ii = 0; ii < 2; ++ii)
#pragma unroll
        for (int jj = 0; jj < 2; ++jj) {
            const int i = bi + ty + 16 * ii;
            const int j = bj + tx + 16 * jj;
            const float* l = acc[ii * 2 + jj];
            const float mm = fmaxf(l[0], fmaxf(l[1], l[2]));
            const float e0 = __expf(l[0] - mm), e1 = __expf(l[1] - mm), e2 = __expf(l[2] - mm);
            const float inv2 = 1.0f / (e0 + e1 + e2);
            float* o = out + ((size_t)i * N + j) * 3;
            o[0] = e0 * inv2; o[1] = e1 * inv2; o[2] = e2 * inv2;
        }
}

extern "C" void kernel_launch(void* const* d_in, const int* in_sizes, int n_in,
                              void* d_out, int out_size, void* d_ws, size_t ws_size,
                              hipStream_t stream)
{
    const float* z    = (const float*)d_in[0];
    const float* dist = (const float*)d_in[1];
    const float* Wq   = (const float*)d_in[2];
    const float* bq   = (const float*)d_in[3];
    const float* Wk   = (const float*)d_in[4];
    const float* bk   = (const float*)d_in[5];
    const float* W1   = (const float*)d_in[6];
    const float* b1   = (const float*)d_in[7];
    const float* W2   = (const float*)d_in[8];
    const float* b2   = (const float*)d_in[9];

    float* out = (float*)d_out;
    float* ws  = (float*)d_ws;
    float*  Q  = ws;
    float*  K  = ws + (size_t)N * D;
    __half* Ah = (__half*)(ws + 2 * (size_t)N * D);
    __half* Bh = Ah + (size_t)N * D;

    proj_kernel<<<N / 8, 256, 0, stream>>>(z, Wq, bq, Wk, bk, W1, b1, Q, K, Ah, Bh);
    score_kernel<<<dim3(N / 32, N / 32), 256, 0, stream>>>(Q, K, dist, out);
    topk_kernel<<<N / 4, 256, 0, stream>>>(out);
    pair_kernel<<<dim3(N / 32, N / 32), 256, 0, stream>>>(Ah, Bh, W2, b2, out + (size_t)N * N);
}

// Round 13
// 160.904 us; speedup vs baseline: 1.0158x; 1.0158x over previous
//
#include <hip/hip_runtime.h>
#include <hip/hip_fp16.h>

#define N 1024
#define D 128

// ---------------- proj: Q,K (f32) + Ah,Bh (f16) = z@{Wq,Wk,W1a,W1b} ----------------
__global__ __launch_bounds__(256) void proj_kernel(
    const float* __restrict__ z,
    const float* __restrict__ Wq, const float* __restrict__ bq,
    const float* __restrict__ Wk, const float* __restrict__ bk,
    const float* __restrict__ W1, const float* __restrict__ b1,
    float* __restrict__ Q, float* __restrict__ Kx,
    __half* __restrict__ Ah, __half* __restrict__ Bh)
{
    const int d  = threadIdx.x & (D - 1);
    const int h  = threadIdx.x >> 7;              // wave-uniform: 0 -> Q/K, 1 -> A/B
    const int r0 = blockIdx.x * 8;
    const float* __restrict__ Wa = h ? W1           : Wq;
    const float* __restrict__ Wb = h ? (W1 + D * D) : Wk;

    float acc0[8] = {0,0,0,0,0,0,0,0};
    float acc1[8] = {0,0,0,0,0,0,0,0};

    for (int c = 0; c < D / 4; ++c) {
        float4 zr[8];
#pragma unroll
        for (int r = 0; r < 8; ++r)
            zr[r] = *(const float4*)&z[(r0 + r) * D + c * 4];
#pragma unroll
        for (int q = 0; q < 4; ++q) {
            const int k = c * 4 + q;
            const float wa = Wa[k * D + d];
            const float wb = Wb[k * D + d];
#pragma unroll
            for (int r = 0; r < 8; ++r) {
                const float zv = (q == 0) ? zr[r].x : (q == 1) ? zr[r].y : (q == 2) ? zr[r].z : zr[r].w;
                acc0[r] = fmaf(zv, wa, acc0[r]);
                acc1[r] = fmaf(zv, wb, acc1[r]);
            }
        }
    }
    if (h == 0) {
        const float c0 = bq[d], c1 = bk[d];
        const float scale = 0.08838834764831845f;   // 1/sqrt(128), folded into Q
#pragma unroll
        for (int r = 0; r < 8; ++r) {
            Q [(r0 + r) * D + d] = (acc0[r] + c0) * scale;
            Kx[(r0 + r) * D + d] = acc1[r] + c1;
        }
    } else {
        const float c0 = b1[d];
#pragma unroll
        for (int r = 0; r < 8; ++r) {
            Ah[(r0 + r) * D + d] = __float2half(acc0[r] + c0);   // b1 folded
            Bh[(r0 + r) * D + d] = __float2half(acc1[r]);
        }
    }
}

// ---------------- scores: S = (Q K^T) * exp(-dist), 32x32 tile (known-good) ----------------
__global__ __launch_bounds__(256) void score_kernel(
    const float* __restrict__ Q, const float* __restrict__ Kx,
    const float* __restrict__ dist, float* __restrict__ S)
{
    __shared__ float Qs[32 * 33 * 4];
    __shared__ float Ks[32 * 33 * 4];
    const int tid = threadIdx.x;
    const int bi = blockIdx.y * 32, bj = blockIdx.x * 32;
    const int tx = tid & 15, ty = tid >> 4;

#pragma unroll
    for (int t = 0; t < 4; ++t) {
        const int e = t * 256 + tid;
        const int row = e >> 5, c = e & 31;
        *(float4*)&Qs[(row * 33 + c) * 4] = *(const float4*)&Q [(size_t)(bi + row) * D + c * 4];
        *(float4*)&Ks[(row * 33 + c) * 4] = *(const float4*)&Kx[(size_t)(bj + row) * D + c * 4];
    }
    __syncthreads();

    const float4* Qs4 = (const float4*)Qs;
    const float4* Ks4 = (const float4*)Ks;
    float a00 = 0.f, a01 = 0.f, a10 = 0.f, a11 = 0.f;

#pragma unroll 4
    for (int c = 0; c < 32; ++c) {
        const float4 q0 = Qs4[ty * 33 + c];
        const float4 q1 = Qs4[(ty + 16) * 33 + c];
        const float4 k0 = Ks4[tx * 33 + c];
        const float4 k1 = Ks4[(tx + 16) * 33 + c];
        a00 = fmaf(q0.x, k0.x, a00); a00 = fmaf(q0.y, k0.y, a00); a00 = fmaf(q0.z, k0.z, a00); a00 = fmaf(q0.w, k0.w, a00);
        a01 = fmaf(q0.x, k1.x, a01); a01 = fmaf(q0.y, k1.y, a01); a01 = fmaf(q0.z, k1.z, a01); a01 = fmaf(q0.w, k1.w, a01);
        a10 = fmaf(q1.x, k0.x, a10); a10 = fmaf(q1.y, k0.y, a10); a10 = fmaf(q1.z, k0.z, a10); a10 = fmaf(q1.w, k0.w, a10);
        a11 = fmaf(q1.x, k1.x, a11); a11 = fmaf(q1.y, k1.y, a11); a11 = fmaf(q1.z, k1.z, a11); a11 = fmaf(q1.w, k1.w, a11);
    }

    const int i0 = bi + ty, i1 = bi + ty + 16;
    const int j0 = bj + tx, j1 = bj + tx + 16;
    S[(size_t)i0 * N + j0] = a00 * __expf(-dist[(size_t)i0 * N + j0]);
    S[(size_t)i0 * N + j1] = a01 * __expf(-dist[(size_t)i0 * N + j1]);
    S[(size_t)i1 * N + j0] = a10 * __expf(-dist[(size_t)i1 * N + j0]);
    S[(size_t)i1 * N + j1] = a11 * __expf(-dist[(size_t)i1 * N + j1]);
}

// ---------------- softmax + top-32 per row; one wave per row (known-good) ----------------
__global__ __launch_bounds__(256) void topk_kernel(float* buf)
{
    const int lane = threadIdx.x & 63;
    const int row  = blockIdx.x * 4 + (threadIdx.x >> 6);
    float* sr = buf + (size_t)row * N;

    float v[16];
#pragma unroll
    for (int c = 0; c < 4; ++c) {
        const float4 f = *(const float4*)&sr[(c * 64 + lane) * 4];
        v[c * 4 + 0] = f.x; v[c * 4 + 1] = f.y; v[c * 4 + 2] = f.z; v[c * 4 + 3] = f.w;
    }
    float m = v[0];
#pragma unroll
    for (int e = 1; e < 16; ++e) m = fmaxf(m, v[e]);
#pragma unroll
    for (int off = 1; off < 64; off <<= 1) m = fmaxf(m, __shfl_xor(m, off));
    float sum = 0.f;
#pragma unroll
    for (int e = 0; e < 16; ++e) sum += __expf(v[e] - m);
#pragma unroll
    for (int off = 1; off < 64; off <<= 1) sum += __shfl_xor(sum, off);
    const float inv = 1.0f / sum;

    unsigned long long key[16];
#pragma unroll
    for (int e = 0; e < 16; ++e) {
        const int j = (((e >> 2) * 64 + lane) * 4) + (e & 3);
        unsigned u = __float_as_uint(v[e]);
        u = (u & 0x80000000u) ? ~u : (u | 0x80000000u);
        key[e] = ((unsigned long long)u << 32) | (unsigned)(N - 1 - j);
    }
    unsigned flags = 0;
    for (int it = 0; it < 32; ++it) {
        unsigned long long best = key[0];
#pragma unroll
        for (int e = 1; e < 16; ++e) best = (key[e] > best) ? key[e] : best;
#pragma unroll
        for (int off = 1; off < 64; off <<= 1) {
            const unsigned long long o = __shfl_xor(best, off);
            if (o > best) best = o;
        }
#pragma unroll
        for (int e = 0; e < 16; ++e)
            if (key[e] == best) { flags |= 1u << e; key[e] = 0ull; }
    }
#pragma unroll
    for (int c = 0; c < 4; ++c) {
        float4 o;
        o.x = (flags & (1u << (c * 4 + 0))) ? __expf(v[c * 4 + 0] - m) * inv : 0.f;
        o.y = (flags & (1u << (c * 4 + 1))) ? __expf(v[c * 4 + 1] - m) * inv : 0.f;
        o.z = (flags & (1u << (c * 4 + 2))) ? __expf(v[c * 4 + 2] - m) * inv : 0.f;
        o.w = (flags & (1u << (c * 4 + 3))) ? __expf(v[c * 4 + 3] - m) * inv : 0.f;
        *(float4*)&sr[(c * 64 + lane) * 4] = o;
    }
}

// ---------------- pairwise gelu classifier + 3-way softmax, f16x2 + exp-sigmoid ----------------
// (r10 configuration — best measured: pair 47.4 us, total 159.6 us)
// gelu(x) = x * sigmoid-form via 2^t; h2exp2/h2rcp saturate correctly at +-inf.
union H2x4 { uint4 u; __half2 h[4]; };

typedef _Float16 v2h __attribute__((ext_vector_type(2)));
union H2V { __half2 h; v2h v; };

__device__ __forceinline__ float fdot2_acc(__half2 a, __half2 b, float c) {
#if __has_builtin(__builtin_amdgcn_fdot2)
    H2V ua, ub;
    ua.h = a; ub.h = b;
    return __builtin_amdgcn_fdot2(ua.v, ub.v, c, false);
#else
    return fmaf(__low2float(a), __low2float(b),
           fmaf(__high2float(a), __high2float(b), c));
#endif
}

#define HP 136   // halves pitch: 272 B rows (16B-aligned)

__global__ __launch_bounds__(256) void pair_kernel(
    const __half* __restrict__ Ah, const __half* __restrict__ Bh,
    const float* __restrict__ W2, const float* __restrict__ b2,
    float* __restrict__ out)
{
    __shared__ __align__(16) __half AsH[32 * HP];
    __shared__ __align__(16) __half BsH[32 * HP];
    __shared__ __align__(16) __half2 Wh[3][68];
    const int tid = threadIdx.x;
    const int bi = blockIdx.y * 32, bj = blockIdx.x * 32;
    const int tx = tid & 15, ty = tid >> 4;

#pragma unroll
    for (int t = 0; t < 2; ++t) {
        const int e = t * 256 + tid;
        const int row = e >> 4, c = e & 15;
        *(uint4*)&AsH[row * HP + c * 8] = *(const uint4*)&Ah[(size_t)(bi + row) * D + c * 8];
        *(uint4*)&BsH[row * HP + c * 8] = *(const uint4*)&Bh[(size_t)(bj + row) * D + c * 8];
    }
    if (tid < 192) {
        const int cls = tid >> 6, dp = tid & 63;
        Wh[cls][dp] = __floats2half2_rn(W2[6 * dp + cls], W2[6 * dp + 3 + cls]);
    }
    const float bb0 = b2[0], bb1 = b2[1], bb2 = b2[2];
    __syncthreads();

    float acc[4][3];
#pragma unroll
    for (int p = 0; p < 4; ++p) { acc[p][0] = bb0; acc[p][1] = bb1; acc[p][2] = bb2; }

    const __half2 C3  = __float2half2_rn(-0.1029434f);
    const __half2 C1  = __float2half2_rn(-2.3022082f);
    const __half2 ONE = __float2half2_rn(1.0f);

#pragma unroll 4
    for (int c = 0; c < 16; ++c) {      // 16 chunks x 8 d
        H2x4 a0, a1, b0, b1, w0, w1, w2;
        a0.u = *(const uint4*)&AsH[ty * HP + c * 8];
        a1.u = *(const uint4*)&AsH[(ty + 16) * HP + c * 8];
        b0.u = *(const uint4*)&BsH[tx * HP + c * 8];
        b1.u = *(const uint4*)&BsH[(tx + 16) * HP + c * 8];
        w0.u = *(const uint4*)&Wh[0][c * 4];    // wave-uniform -> LDS broadcast
        w1.u = *(const uint4*)&Wh[1][c * 4];
        w2.u = *(const uint4*)&Wh[2][c * 4];
#pragma unroll
        for (int dp = 0; dp < 4; ++dp) {
            const __half2 aa[2] = { a0.h[dp], a1.h[dp] };
            const __half2 bb[2] = { b0.h[dp], b1.h[dp] };
            const __half2 wc0 = w0.h[dp], wc1 = w1.h[dp], wc2 = w2.h[dp];
#pragma unroll
            for (int ii = 0; ii < 2; ++ii)
#pragma unroll
                for (int jj = 0; jj < 2; ++jj) {
                    const __half2 x = __hadd2(aa[ii], bb[jj]);
                    const __half2 u = __hmul2(x, x);
                    const __half2 p = __hfma2(C3, u, C1);
                    const __half2 t = __hmul2(x, p);
                    const __half2 e = h2exp2(t);          // 2^t ; under/overflow -> 0/inf (correct limits)
                    const __half2 dn = __hadd2(e, ONE);
                    const __half2 r = h2rcp(dn);          // rcp(inf)=0 -> g=0 (correct)
                    const __half2 g = __hmul2(x, r);
                    float* l = acc[ii * 2 + jj];
                    l[0] = fdot2_acc(g, wc0, l[0]);
                    l[1] = fdot2_acc(g, wc1, l[1]);
                    l[2] = fdot2_acc(g, wc2, l[2]);
                }
        }
    }

#pragma unroll
    for (int ii = 0; ii < 2; ++ii)
#pragma unroll
        for (int jj = 0; jj < 2; ++jj) {
            const int i = bi + ty + 16 * ii;
            const int j = bj + tx + 16 * jj;
            const float* l = acc[ii * 2 + jj];
            const float mm = fmaxf(l[0], fmaxf(l[1], l[2]));
            const float e0 = __expf(l[0] - mm), e1 = __expf(l[1] - mm), e2 = __expf(l[2] - mm);
            const float inv2 = 1.0f / (e0 + e1 + e2);
            float* o = out + ((size_t)i * N + j) * 3;
            o[0] = e0 * inv2; o[1] = e1 * inv2; o[2] = e2 * inv2;
        }
}

extern "C" void kernel_launch(void* const* d_in, const int* in_sizes, int n_in,
                              void* d_out, int out_size, void* d_ws, size_t ws_size,
                              hipStream_t stream)
{
    const float* z    = (const float*)d_in[0];
    const float* dist = (const float*)d_in[1];
    const float* Wq   = (const float*)d_in[2];
    const float* bq   = (const float*)d_in[3];
    const float* Wk   = (const float*)d_in[4];
    const float* bk   = (const float*)d_in[5];
    const float* W1   = (const float*)d_in[6];
    const float* b1   = (const float*)d_in[7];
    const float* W2   = (const float*)d_in[8];
    const float* b2   = (const float*)d_in[9];

    float* out = (float*)d_out;
    float* ws  = (float*)d_ws;
    float*  Q  = ws;
    float*  K  = ws + (size_t)N * D;
    __half* Ah = (__half*)(ws + 2 * (size_t)N * D);
    __half* Bh = Ah + (size_t)N * D;

    proj_kernel<<<N / 8, 256, 0, stream>>>(z, Wq, bq, Wk, bk, W1, b1, Q, K, Ah, Bh);
    score_kernel<<<dim3(N / 32, N / 32), 256, 0, stream>>>(Q, K, dist, out);
    topk_kernel<<<N / 4, 256, 0, stream>>>(out);
    pair_kernel<<<dim3(N / 32, N / 32), 256, 0, stream>>>(Ah, Bh, W2, b2, out + (size_t)N * N);
}